// Round 2
// baseline (605.417 us; speedup 1.0000x reference)
//
#include <hip/hip_runtime.h>
#include <math.h>

typedef unsigned short u16;
typedef unsigned int u32;
typedef short s16x8 __attribute__((ext_vector_type(8)));
typedef float f32x4 __attribute__((ext_vector_type(4)));
typedef u16 u16x4 __attribute__((ext_vector_type(4)));

__device__ __forceinline__ u16 f2bf(float x) {
  u32 u = __float_as_uint(x);
  u32 r = u + 0x7FFFu + ((u >> 16) & 1u);  // round-to-nearest-even
  return (u16)(r >> 16);
}
__device__ __forceinline__ float bf2f(u16 h) {
  return __uint_as_float(((u32)h) << 16);
}
__device__ __forceinline__ void splitbf(float x, u16 &hi, u16 &lo) {
  hi = f2bf(x);
  lo = f2bf(x - bf2f(hi));
}

__device__ __forceinline__ void gload16(const void* g, void* l) {
  __builtin_amdgcn_global_load_lds(
      (const __attribute__((address_space(1))) void*)g,
      (__attribute__((address_space(3))) void*)l, 16, 0, 0);
}

// ---------------------------------------------------------------------------
// 8-phase 256-wide NT GEMM (m201-style template, plain HIP).
// A [M,K] rm, B [N,K] rm, C[m][n] = sum_k A[m][k]*B[n][k].
// Tile BM=256 x BN=64*JF (JF=4 -> 256, JF=2 -> 128), BK=64, 8 waves (2Mx4N),
// per-wave 128 x 16*JF, acc[8][JF] of 16x16 frags, mfma_f32_16x16x32_bf16.
// LDS: 2 buffers x (A 32KB + B JF*8KB); halves of 128 rows x 64 cols, XOR
// slot swizzle (slot ^= row&7) with pre-swizzled global source (rule #21).
// Phase p: ds_read A-frags {2p,2p+1} (+ all B at p0), issue stages, barrier,
// lgkmcnt(0), setprio(1), MFMA cluster, setprio(0), [p3: counted vmcnt],
// barrier.  Staging map (half s, cur=s&1):
//   p0: A.h0(s+1)->buf[cur^1]   (A of buf[cur^1] last read in prev half p3)
//   p1: A.h1(s+1)->buf[cur^1];  B.h0(s+2)->buf[cur] (B last read at p0)
//   p2: B.h1(s+2)->buf[cur]     (JF==4 only)
//   p3: vmcnt(4|2) -> drains exactly tile s+1; B(s+2) stays in flight.
// EPI: 0=qkv split3, 1=scores f32, 2=+resid f32, 3=+bias+gelu->bf16,
//      4=+bias+resid->f32 (final out)
// ---------------------------------------------------------------------------
template <int JF, int EPI, bool SWZ>
__global__ __launch_bounds__(512, 2) void gemm8(
    const u16* __restrict__ A, const u16* __restrict__ B, int M, int N, int K,
    long zsA, long zsB, long zsC, float* __restrict__ outF,
    u16* __restrict__ outU, u16* __restrict__ outU2, u16* __restrict__ outU3,
    const float* __restrict__ aux0, const float* __restrict__ aux1) {
  constexpr int BUF = 32768 + JF * 8192;  // bytes per double-buffer half
  extern __shared__ __align__(16) char smem[];

  const int tid = threadIdx.x;
  const int lane = tid & 63;
  const int wave = tid >> 6;
  const int z = blockIdx.z;

  int bx = blockIdx.x, by = blockIdx.y;
  if constexpr (SWZ) {
    const int gx = gridDim.x;
    const int nwg = gx * gridDim.y;
    const int id = by * gx + bx;
    const int q = nwg >> 3;               // nwg % 8 == 0 for all our grids
    const int id2 = (id & 7) * q + (id >> 3);
    bx = id2 % gx;
    by = id2 / gx;
  }
  const long row0 = (long)by * 256;
  const long col0 = (long)bx * (64 * JF);

  const u16* __restrict__ Ab = A + (long)z * zsA;
  const u16* __restrict__ Bb = B + (long)z * zsB;

  // staging lane geometry (pre-swizzled global slot, linear LDS dest)
  const int srow = lane >> 3;
  const int gslot = (lane & 7) ^ srow;
  // fragment lane geometry
  const int fr = lane & 15;
  const int kgrp = lane >> 4;
  const int wm = (wave >> 2) << 7;        // 0 or 128
  const int wn = (wave & 3) * (16 * JF);  // 64-col (JF=4) or 32-col slices

  const int nk = K >> 6;

  f32x4 acc[8][JF] = {};
  s16x8 bfrag[2][JF];

  auto stageA = [&](int buf, int kt, int h) {
#pragma unroll
    for (int l = 0; l < 2; ++l) {
      const int c = wave * 2 + l;  // 16 chunks of 8 rows per 128-row half
      gload16(Ab + (row0 + h * 128 + c * 8 + srow) * (long)K +
                  ((long)kt << 6) + gslot * 8,
              smem + buf * BUF + h * 16384 + c * 1024 + lane * 16);
    }
  };
  auto stageB = [&](int buf, int kt, int h) {
#pragma unroll
    for (int l = 0; l < 2; ++l) {
      const int c = wave * 2 + l;
      gload16(Bb + (col0 + h * 128 + c * 8 + srow) * (long)K +
                  ((long)kt << 6) + gslot * 8,
              smem + buf * BUF + 32768 + h * 16384 + c * 1024 + lane * 16);
    }
  };
  auto readA = [&](int buf, int i, int kk) -> s16x8 {
    const int r = wm + i * 16 + fr;
    const int hr = r & 127;
    const int slot = ((kk << 2) | kgrp) ^ (hr & 7);
    return *(const s16x8*)(smem + buf * BUF + ((r >> 7) << 14) + hr * 128 +
                           slot * 16);
  };
  auto readB = [&](int buf, int j, int kk) -> s16x8 {
    const int r = wn + j * 16 + fr;
    const int hr = r & 127;
    const int slot = ((kk << 2) | kgrp) ^ (hr & 7);
    return *(const s16x8*)(smem + buf * BUF + 32768 + ((r >> 7) << 14) +
                           hr * 128 + slot * 16);
  };

  // prologue: tile0 (A+B) -> buf0; tile1's B -> buf1.  Drain tile0 only.
  stageA(0, 0, 0);
  stageA(0, 0, 1);
  stageB(0, 0, 0);
  if constexpr (JF == 4) stageB(0, 0, 1);
  stageB(1, 1, 0);
  if constexpr (JF == 4) stageB(1, 1, 1);
  if constexpr (JF == 4)
    asm volatile("s_waitcnt vmcnt(4)");
  else
    asm volatile("s_waitcnt vmcnt(2)");
  __builtin_amdgcn_s_barrier();

  for (int s = 0; s < nk; ++s) {
    const int cur = s & 1;
    const bool stA = (s + 1 < nk);
    const bool stB = (s + 2 < nk);
#pragma unroll
    for (int p = 0; p < 4; ++p) {
      s16x8 a00 = readA(cur, 2 * p, 0);
      s16x8 a01 = readA(cur, 2 * p, 1);
      s16x8 a10 = readA(cur, 2 * p + 1, 0);
      s16x8 a11 = readA(cur, 2 * p + 1, 1);
      if (p == 0) {
#pragma unroll
        for (int j = 0; j < JF; ++j) {
          bfrag[0][j] = readB(cur, j, 0);
          bfrag[1][j] = readB(cur, j, 1);
        }
      }
      if (p == 0 && stA) stageA(cur ^ 1, s + 1, 0);
      if (p == 1) {
        if (stA) stageA(cur ^ 1, s + 1, 1);
        if (stB) stageB(cur, s + 2, 0);
      }
      if (p == 2 && stB) {
        if constexpr (JF == 4) stageB(cur, s + 2, 1);
      }
      __builtin_amdgcn_s_barrier();
      asm volatile("s_waitcnt lgkmcnt(0)");
      __builtin_amdgcn_s_setprio(1);
#pragma unroll
      for (int j = 0; j < JF; ++j) {
        acc[2 * p][j] = __builtin_amdgcn_mfma_f32_16x16x32_bf16(
            a00, bfrag[0][j], acc[2 * p][j], 0, 0, 0);
        acc[2 * p + 1][j] = __builtin_amdgcn_mfma_f32_16x16x32_bf16(
            a10, bfrag[0][j], acc[2 * p + 1][j], 0, 0, 0);
      }
#pragma unroll
      for (int j = 0; j < JF; ++j) {
        acc[2 * p][j] = __builtin_amdgcn_mfma_f32_16x16x32_bf16(
            a01, bfrag[1][j], acc[2 * p][j], 0, 0, 0);
        acc[2 * p + 1][j] = __builtin_amdgcn_mfma_f32_16x16x32_bf16(
            a11, bfrag[1][j], acc[2 * p + 1][j], 0, 0, 0);
      }
      __builtin_amdgcn_s_setprio(0);
      if (p == 3) {
        if (stB) {
          if constexpr (JF == 4)
            asm volatile("s_waitcnt vmcnt(4)");
          else
            asm volatile("s_waitcnt vmcnt(2)");
        } else {
          asm volatile("s_waitcnt vmcnt(0)");
        }
      }
      __builtin_amdgcn_s_barrier();
    }
  }

  // epilogue: C/D frag layout: col = lane&15 (fr), row = kgrp*4 + r
#pragma unroll
  for (int i = 0; i < 8; ++i) {
#pragma unroll
    for (int j = 0; j < JF; ++j) {
#pragma unroll
      for (int r = 0; r < 4; ++r) {
        const long m = row0 + wm + i * 16 + (kgrp << 2) + r;
        const long n = col0 + wn + j * 16 + fr;
        const float val = acc[i][j][r];
        if constexpr (EPI == 0) {
          // qkv: n<1024 -> q3 (hi,lo,hi); n<2048 -> k3 (hi,hi,lo); else v bf16
          if (n < 1024) {
            u16 hi, lo; splitbf(val, hi, lo);
            u16* p = outU + m * 3072 + n;
            p[0] = hi; p[1024] = lo; p[2048] = hi;
          } else if (n < 2048) {
            u16 hi, lo; splitbf(val, hi, lo);
            u16* p = outU2 + m * 3072 + (n - 1024);
            p[0] = hi; p[1024] = hi; p[2048] = lo;
          } else {
            outU3[m * 1024 + (n - 2048)] = f2bf(val);
          }
        } else if constexpr (EPI == 1) {
          outF[(long)z * zsC + m * (long)N + n] = val;
        } else if constexpr (EPI == 2) {
          const long idx = (long)z * zsC + m * (long)N + n;
          outF[idx] = val + aux0[idx];
        } else if constexpr (EPI == 3) {
          const float t = val + aux0[n];
          const float gl = 0.5f * t * (1.0f + erff(t * 0.70710678118654752f));
          outU[m * (long)N + n] = f2bf(gl);
        } else {
          outF[m * (long)N + n] = val + aux0[n] + aux1[m * (long)N + n];
        }
      }
    }
  }
}

// ---------------------------------------------------------------------------
// LayerNorm over D=1024, one wave per row, 4 rows/block.
// ---------------------------------------------------------------------------
template <bool SPLIT3>
__global__ __launch_bounds__(256) void ln_k(const float* __restrict__ x,
                                            const float* __restrict__ gw,
                                            const float* __restrict__ bw,
                                            u16* __restrict__ out) {
  const int lane = threadIdx.x & 63;
  const int wv = threadIdx.x >> 6;
  const long row = (long)blockIdx.x * 4 + wv;
  const float* xr = x + row * 1024;
  float4 v[4];
  float s = 0.f, ss = 0.f;
#pragma unroll
  for (int j = 0; j < 4; ++j) {
    v[j] = *(const float4*)(xr + (lane + 64 * j) * 4);
    s += v[j].x + v[j].y + v[j].z + v[j].w;
    ss += v[j].x * v[j].x + v[j].y * v[j].y + v[j].z * v[j].z + v[j].w * v[j].w;
  }
#pragma unroll
  for (int o = 32; o; o >>= 1) {
    s += __shfl_xor(s, o);
    ss += __shfl_xor(ss, o);
  }
  const float mu = s * (1.f / 1024.f);
  const float var = ss * (1.f / 1024.f) - mu * mu;
  const float rs = rsqrtf(var + 1e-5f);
  u16* orow = out + row * (SPLIT3 ? 3072 : 1024);
#pragma unroll
  for (int j = 0; j < 4; ++j) {
    const int n = (lane + 64 * j) * 4;
    const float4 gg = *(const float4*)(gw + n);
    const float4 bb = *(const float4*)(bw + n);
    const float y[4] = {(v[j].x - mu) * rs * gg.x + bb.x,
                        (v[j].y - mu) * rs * gg.y + bb.y,
                        (v[j].z - mu) * rs * gg.z + bb.z,
                        (v[j].w - mu) * rs * gg.w + bb.w};
    u16x4 H, L;
#pragma unroll
    for (int c = 0; c < 4; ++c) {
      u16 hi, lo; splitbf(y[c], hi, lo);
      H[c] = hi; L[c] = lo;
    }
    if constexpr (SPLIT3) {
      *(u16x4*)(orow + n) = H;
      *(u16x4*)(orow + 1024 + n) = L;
      *(u16x4*)(orow + 2048 + n) = H;
    } else {
      *(u16x4*)(orow + n) = H;
    }
  }
}

// ---------------------------------------------------------------------------
// Tiled transpose+convert. in [R,C] -> out [C,R] (per z).
// MODE 0: f32 -> bf16; MODE 1: f32 -> split3 [C,3R] = (hi|hi|lo);
// MODE 2: bf16 -> bf16.
// ---------------------------------------------------------------------------
template <int MODE>
__global__ __launch_bounds__(256) void transpose_k(const void* __restrict__ in,
                                                   u16* __restrict__ out, int R,
                                                   int C, long zsIn, long zsOut) {
  __shared__ float tile[32][33];
  const int z = blockIdx.z;
  const int c0 = blockIdx.x * 32, r0 = blockIdx.y * 32;
#pragma unroll
  for (int i = 0; i < 4; ++i) {
    const int lin = threadIdx.x + 256 * i;
    const int rr = lin >> 5, cc = lin & 31;
    float vv;
    if constexpr (MODE == 2)
      vv = bf2f(((const u16*)in + (long)z * zsIn)[(long)(r0 + rr) * C + c0 + cc]);
    else
      vv = ((const float*)in)[(long)(r0 + rr) * C + c0 + cc];
    tile[rr][cc] = vv;
  }
  __syncthreads();
  u16* outz = out + (long)z * zsOut;
#pragma unroll
  for (int i = 0; i < 4; ++i) {
    const int lin = threadIdx.x + 256 * i;
    const int oc = lin >> 5, orr = lin & 31;
    const float vv = tile[orr][oc];
    if constexpr (MODE == 1) {
      u16 hi, lo; splitbf(vv, hi, lo);
      u16* p = out + (long)(c0 + oc) * (3L * R) + (r0 + orr);
      p[0] = hi; p[R] = hi; p[2 * R] = lo;
    } else {
      outz[(long)(c0 + oc) * R + (r0 + orr)] = f2bf(vv);
    }
  }
}

// ---------------------------------------------------------------------------
// Row softmax over 2048 cols, f32 in -> bf16 out. One block (256 thr) per row.
// ---------------------------------------------------------------------------
__global__ __launch_bounds__(256) void softmax_k(const float* __restrict__ S,
                                                 u16* __restrict__ P) {
  const long row = blockIdx.x;
  const float* sr = S + row * 2048;
  u16* pr = P + row * 2048;
  const int tid = threadIdx.x;
  const int lane = tid & 63, wv = tid >> 6;
  __shared__ float red[8];
  const float4 v0 = *(const float4*)(sr + tid * 4);
  const float4 v1 = *(const float4*)(sr + 1024 + tid * 4);
  float mx = fmaxf(fmaxf(fmaxf(v0.x, v0.y), fmaxf(v0.z, v0.w)),
                   fmaxf(fmaxf(v1.x, v1.y), fmaxf(v1.z, v1.w)));
#pragma unroll
  for (int o = 32; o; o >>= 1) mx = fmaxf(mx, __shfl_xor(mx, o));
  if (lane == 0) red[wv] = mx;
  __syncthreads();
  mx = fmaxf(fmaxf(red[0], red[1]), fmaxf(red[2], red[3]));
  float e[8];
  e[0] = expf(v0.x - mx); e[1] = expf(v0.y - mx);
  e[2] = expf(v0.z - mx); e[3] = expf(v0.w - mx);
  e[4] = expf(v1.x - mx); e[5] = expf(v1.y - mx);
  e[6] = expf(v1.z - mx); e[7] = expf(v1.w - mx);
  float sm = e[0] + e[1] + e[2] + e[3] + e[4] + e[5] + e[6] + e[7];
#pragma unroll
  for (int o = 32; o; o >>= 1) sm += __shfl_xor(sm, o);
  if (lane == 0) red[4 + wv] = sm;
  __syncthreads();
  sm = red[4] + red[5] + red[6] + red[7];
  const float inv = 1.f / sm;
  u16x4 a, b;
  a[0] = f2bf(e[0] * inv); a[1] = f2bf(e[1] * inv);
  a[2] = f2bf(e[2] * inv); a[3] = f2bf(e[3] * inv);
  b[0] = f2bf(e[4] * inv); b[1] = f2bf(e[5] * inv);
  b[2] = f2bf(e[6] * inv); b[3] = f2bf(e[7] * inv);
  *(u16x4*)(pr + tid * 4) = a;
  *(u16x4*)(pr + 1024 + tid * 4) = b;
}

// ---------------------------------------------------------------------------
extern "C" void kernel_launch(void* const* d_in, const int* in_sizes, int n_in,
                              void* d_out, int out_size, void* d_ws,
                              size_t ws_size, hipStream_t stream) {
  const float* x      = (const float*)d_in[0];  // [4,2048,1024]
  const float* w_qkv  = (const float*)d_in[1];  // [1024,3072]
  const float* fc1_w  = (const float*)d_in[2];  // [1024,4096]
  const float* fc1_b  = (const float*)d_in[3];  // [4096]
  const float* fc2_w  = (const float*)d_in[4];  // [4096,1024]
  const float* fc2_b  = (const float*)d_in[5];  // [1024]
  const float* ln1_g  = (const float*)d_in[6];
  const float* ln1_b  = (const float*)d_in[7];
  const float* ln2_g  = (const float*)d_in[8];
  const float* ln2_b  = (const float*)d_in[9];
  float* out = (float*)d_out;

  // workspace layout (phase-aliased; peak 178 MB)
  char* ws = (char*)d_ws;
  const long MB = 1024L * 1024L;
  u16*   h3   = (u16*)(ws + 0);         // 48MB [8192,3072] (hi|lo|hi)
  u16*   wq3  = (u16*)(ws + 48 * MB);   // 18MB [3072,3072] (hi|hi|lo)
  u16*   q3   = (u16*)(ws + 66 * MB);   // 48MB
  u16*   k3   = (u16*)(ws + 114 * MB);  // 48MB
  u16*   vbuf = (u16*)(ws + 162 * MB);  // 16MB [8192,1024]
  float* sc   = (float*)(ws + 0);       // 64MB scores (h3/wq3 dead)
  u16*   P    = (u16*)(ws + 64 * MB);   // 32MB (q3 dead after GEMM2)
  u16*   vT   = (u16*)(ws + 96 * MB);   // 16MB [4][1024][2048]
  float* r2   = (float*)(ws + 112 * MB);// 32MB (k3 dead)
  u16*   h2   = (u16*)(ws + 144 * MB);  // 16MB
  u16*   w1T  = (u16*)(ws + 160 * MB);  //  8MB [4096,1024]
  u16*   w2T  = (u16*)(ws + 168 * MB);  //  8MB [1024,4096]
  u16*   g    = (u16*)(ws + 0);         // 64MB [8192,4096] (scores dead)

  dim3 blk(256);
  dim3 blk8(512);
  const int LDS4 = 131072;  // JF=4: 2 x (32KB A + 32KB B)
  const int LDS2 = 98304;   // JF=2: 2 x (32KB A + 16KB B)
  (void)hipFuncSetAttribute((const void*)gemm8<4, 0, true>,
                            hipFuncAttributeMaxDynamicSharedMemorySize, LDS4);
  (void)hipFuncSetAttribute((const void*)gemm8<4, 1, false>,
                            hipFuncAttributeMaxDynamicSharedMemorySize, LDS4);
  (void)hipFuncSetAttribute((const void*)gemm8<2, 2, false>,
                            hipFuncAttributeMaxDynamicSharedMemorySize, LDS2);
  (void)hipFuncSetAttribute((const void*)gemm8<4, 3, true>,
                            hipFuncAttributeMaxDynamicSharedMemorySize, LDS4);
  (void)hipFuncSetAttribute((const void*)gemm8<2, 4, true>,
                            hipFuncAttributeMaxDynamicSharedMemorySize, LDS2);

  // 1) LN1 -> h3 (split3 A-operand)
  ln_k<true><<<2048, blk, 0, stream>>>(x, ln1_g, ln1_b, h3);
  // 2) w_qkv [1024,3072] -> wq3 [3072,3072] (split3 B-operand)
  transpose_k<1><<<dim3(3072 / 32, 1024 / 32, 1), blk, 0, stream>>>(
      w_qkv, wq3, 1024, 3072, 0, 0);
  // 3) GEMM1 (emulated-fp32): qkv = h @ w_qkv -> q3,k3,v
  gemm8<4, 0, true><<<dim3(12, 32, 1), blk8, LDS4, stream>>>(
      h3, wq3, 8192, 3072, 3072, 0, 0, 0, nullptr, q3, k3, vbuf, nullptr,
      nullptr);
  // 4) GEMM2 (emulated-fp32): scores[b] = q[b] @ k[b]^T
  gemm8<4, 1, false><<<dim3(8, 8, 4), blk8, LDS4, stream>>>(
      q3, k3, 2048, 2048, 3072, 2048L * 3072, 2048L * 3072, 2048L * 2048, sc,
      nullptr, nullptr, nullptr, nullptr, nullptr);
  // 5) v [b][2048,1024] -> vT [b][1024,2048]
  transpose_k<2><<<dim3(1024 / 32, 2048 / 32, 4), blk, 0, stream>>>(
      vbuf, vT, 2048, 1024, 2048L * 1024, 1024L * 2048);
  // 6) softmax rows -> P bf16
  softmax_k<<<8192, blk, 0, stream>>>(sc, P);
  // 7) GEMM3: attn[b] = P[b] @ v[b]; += residual x -> r2
  gemm8<2, 2, false><<<dim3(8, 8, 4), blk8, LDS2, stream>>>(
      P, vT, 2048, 1024, 2048, 2048L * 2048, 1024L * 2048, 2048L * 1024, r2,
      nullptr, nullptr, nullptr, x, nullptr);
  // 8) LN2 -> h2 bf16
  ln_k<false><<<2048, blk, 0, stream>>>(r2, ln2_g, ln2_b, h2);
  // 9) fc1_w [1024,4096] -> w1T [4096,1024] bf16
  transpose_k<0><<<dim3(4096 / 32, 1024 / 32, 1), blk, 0, stream>>>(
      fc1_w, w1T, 1024, 4096, 0, 0);
  // 10) fc2_w [4096,1024] -> w2T [1024,4096] bf16
  transpose_k<0><<<dim3(1024 / 32, 4096 / 32, 1), blk, 0, stream>>>(
      fc2_w, w2T, 4096, 1024, 0, 0);
  // 11) GEMM4: g = gelu(h2 @ fc1_w + b1) bf16
  gemm8<4, 3, true><<<dim3(16, 32, 1), blk8, LDS4, stream>>>(
      h2, w1T, 8192, 4096, 1024, 0, 0, 0, nullptr, g, nullptr, nullptr, fc1_b,
      nullptr);
  // 12) GEMM5: out = g @ fc2_w + b2 + r2
  gemm8<2, 4, true><<<dim3(8, 32, 1), blk8, LDS2, stream>>>(
      g, w2T, 8192, 1024, 4096, 0, 0, 0, out, nullptr, nullptr, nullptr, fc2_b,
      r2);
}

// Round 3
// 528.058 us; speedup vs baseline: 1.1465x; 1.1465x over previous
//
#include <hip/hip_runtime.h>
#include <math.h>

typedef unsigned short u16;
typedef unsigned int u32;
typedef short s16x8 __attribute__((ext_vector_type(8)));
typedef float f32x4 __attribute__((ext_vector_type(4)));
typedef u16 u16x4 __attribute__((ext_vector_type(4)));

__device__ __forceinline__ u16 f2bf(float x) {
  u32 u = __float_as_uint(x);
  u32 r = u + 0x7FFFu + ((u >> 16) & 1u);  // round-to-nearest-even
  return (u16)(r >> 16);
}
__device__ __forceinline__ float bf2f(u16 h) {
  return __uint_as_float(((u32)h) << 16);
}
__device__ __forceinline__ void splitbf(float x, u16 &hi, u16 &lo) {
  hi = f2bf(x);
  lo = f2bf(x - bf2f(hi));
}

__device__ __forceinline__ void gload16(const void* g, void* l) {
  __builtin_amdgcn_global_load_lds(
      (const __attribute__((address_space(1))) void*)g,
      (__attribute__((address_space(3))) void*)l, 16, 0, 0);
}

// ---------------------------------------------------------------------------
// 8-phase NT GEMM (m201-style).  A [M,lda] rm, B [N,ldb] rm,
// C[m][n] = sum_k A[m][k]*B[n][k] over logical K (TRIPLE: K=3072 maps into
// 2048-wide [hi|lo] storage: A=(hi,lo,hi) ktA=kt<32?kt:kt-32,
// B=(hi,hi,lo) ktB=kt<16?kt:kt-16).
// Tile 256 x (64*JF), BK=64, 8 waves (2Mx4N), per-wave 128 x 16*JF,
// mfma_f32_16x16x32_bf16.  NPH phases/tile (JF=4 -> 4, JF=2 -> 2), each
// phase: ds_read A-frags (+all B at p0), issue stages, barrier, lgkmcnt(0),
// setprio(1), 16 MFMA, setprio(0), [last: counted vmcnt], barrier.
// Steady-state drain keeps B(s+2) in flight (vmcnt(JF)).
// EPI: 0=qk split2-writer, 1=scores f32, 2=+resid f32, 3=+bias+gelu->bf16,
//      4=+bias+resid->f32, 5=plain bf16
// ---------------------------------------------------------------------------
template <int JF, int NPH, int EPI, bool TRIPLE, bool SWZ>
__global__ __launch_bounds__(512, 2) void gemm8(
    const u16* __restrict__ A, const u16* __restrict__ B, int M, int N, int K,
    int lda, int ldb, long zsA, long zsB, long zsC, float* __restrict__ outF,
    u16* __restrict__ outU, u16* __restrict__ outU2,
    const float* __restrict__ aux0, const float* __restrict__ aux1) {
  constexpr int BUF = 32768 + JF * 8192;  // bytes per double-buffer half
  constexpr int IPP = 8 / NPH;            // i-frags per phase
  extern __shared__ __align__(16) char smem[];

  const int tid = threadIdx.x;
  const int lane = tid & 63;
  const int wave = tid >> 6;
  const int z = blockIdx.z;

  int bx = blockIdx.x, by = blockIdx.y;
  if constexpr (SWZ) {
    const int gx = gridDim.x;
    const int nwg = gx * gridDim.y;
    const int id = by * gx + bx;
    const int q = nwg >> 3;  // nwg % 8 == 0 for all our grids
    const int id2 = (id & 7) * q + (id >> 3);
    bx = id2 % gx;
    by = id2 / gx;
  }
  const long row0 = (long)by * 256;
  const long col0 = (long)bx * (64 * JF);

  const u16* __restrict__ Ab = A + (long)z * zsA;
  const u16* __restrict__ Bb = B + (long)z * zsB;

  // staging lane geometry (pre-swizzled global slot, linear LDS dest)
  const int srow = lane >> 3;
  const int gslot = (lane & 7) ^ srow;
  // fragment lane geometry
  const int fr = lane & 15;
  const int kgrp = lane >> 4;
  const int wm = (wave >> 2) << 7;        // 0 or 128
  const int wn = (wave & 3) * (16 * JF);

  const int nk = K >> 6;

  f32x4 acc[8][JF] = {};
  s16x8 bfrag[2][JF];

  auto stageA = [&](int buf, int kt, int h) {
    const int ktm = TRIPLE ? (kt < 32 ? kt : kt - 32) : kt;
#pragma unroll
    for (int l = 0; l < 2; ++l) {
      const int c = wave * 2 + l;  // 16 chunks of 8 rows per 128-row half
      gload16(Ab + (row0 + h * 128 + c * 8 + srow) * (long)lda + ktm * 64 +
                  gslot * 8,
              smem + buf * BUF + h * 16384 + c * 1024 + lane * 16);
    }
  };
  auto stageB = [&](int buf, int kt, int h) {
    const int ktm = TRIPLE ? (kt < 16 ? kt : kt - 16) : kt;
#pragma unroll
    for (int l = 0; l < 2; ++l) {
      const int c = wave * 2 + l;
      gload16(Bb + (col0 + h * 128 + c * 8 + srow) * (long)ldb + ktm * 64 +
                  gslot * 8,
              smem + buf * BUF + 32768 + h * 16384 + c * 1024 + lane * 16);
    }
  };
  auto readA = [&](int buf, int i, int kk) -> s16x8 {
    const int r = wm + i * 16 + fr;
    const int hr = r & 127;
    const int slot = ((kk << 2) | kgrp) ^ (hr & 7);
    return *(const s16x8*)(smem + buf * BUF + ((r >> 7) << 14) + hr * 128 +
                           slot * 16);
  };
  auto readB = [&](int buf, int j, int kk) -> s16x8 {
    const int r = wn + j * 16 + fr;
    const int hr = r & 127;
    const int slot = ((kk << 2) | kgrp) ^ (hr & 7);
    return *(const s16x8*)(smem + buf * BUF + 32768 + ((r >> 7) << 14) +
                           hr * 128 + slot * 16);
  };

  // prologue: tile0 (A+B) -> buf0; tile1's B -> buf1.  Drain tile0 only.
  stageA(0, 0, 0);
  stageA(0, 0, 1);
  stageB(0, 0, 0);
  if constexpr (JF == 4) stageB(0, 0, 1);
  stageB(1, 1, 0);
  if constexpr (JF == 4) stageB(1, 1, 1);
  if constexpr (JF == 4)
    asm volatile("s_waitcnt vmcnt(4)");
  else
    asm volatile("s_waitcnt vmcnt(2)");
  __builtin_amdgcn_s_barrier();

  for (int s = 0; s < nk; ++s) {
    const int cur = s & 1;
    const bool stA = (s + 1 < nk);
    const bool stB = (s + 2 < nk);
#pragma unroll
    for (int p = 0; p < NPH; ++p) {
      s16x8 af[IPP][2];
#pragma unroll
      for (int ii = 0; ii < IPP; ++ii) {
        af[ii][0] = readA(cur, p * IPP + ii, 0);
        af[ii][1] = readA(cur, p * IPP + ii, 1);
      }
      if (p == 0) {
#pragma unroll
        for (int j = 0; j < JF; ++j) {
          bfrag[0][j] = readB(cur, j, 0);
          bfrag[1][j] = readB(cur, j, 1);
        }
      }
      // staging map
      if (p == 0 && stA) stageA(cur ^ 1, s + 1, 0);
      if (p == 1) {
        if (stA) stageA(cur ^ 1, s + 1, 1);
        if (stB) stageB(cur, s + 2, 0);
      }
      if constexpr (NPH == 4) {
        if (p == 2 && stB) stageB(cur, s + 2, 1);
      }
      __builtin_amdgcn_s_barrier();
      asm volatile("s_waitcnt lgkmcnt(0)");
      __builtin_amdgcn_s_setprio(1);
#pragma unroll
      for (int kk = 0; kk < 2; ++kk)
#pragma unroll
        for (int ii = 0; ii < IPP; ++ii)
#pragma unroll
          for (int j = 0; j < JF; ++j)
            acc[p * IPP + ii][j] = __builtin_amdgcn_mfma_f32_16x16x32_bf16(
                af[ii][kk], bfrag[kk][j], acc[p * IPP + ii][j], 0, 0, 0);
      __builtin_amdgcn_s_setprio(0);
      if (p == NPH - 1) {
        if (stB) {
          if constexpr (JF == 4)
            asm volatile("s_waitcnt vmcnt(4)");
          else
            asm volatile("s_waitcnt vmcnt(2)");
        } else {
          asm volatile("s_waitcnt vmcnt(0)");
        }
      }
      __builtin_amdgcn_s_barrier();
    }
  }

  // epilogue: C/D frag layout: col = lane&15 (fr), row = kgrp*4 + r
#pragma unroll
  for (int i = 0; i < 8; ++i) {
#pragma unroll
    for (int j = 0; j < JF; ++j) {
#pragma unroll
      for (int r = 0; r < 4; ++r) {
        const long m = row0 + wm + i * 16 + (kgrp << 2) + r;
        const long n = col0 + wn + j * 16 + fr;
        const float val = acc[i][j][r];
        if constexpr (EPI == 0) {
          // qk: n<1024 -> q2 [hi|lo]; else k2 [hi|lo]
          u16 hi, lo;
          splitbf(val, hi, lo);
          if (n < 1024) {
            u16* p = outU + m * 2048 + n;
            p[0] = hi;
            p[1024] = lo;
          } else {
            u16* p = outU2 + m * 2048 + (n - 1024);
            p[0] = hi;
            p[1024] = lo;
          }
        } else if constexpr (EPI == 1) {
          outF[(long)z * zsC + m * (long)N + n] = val;
        } else if constexpr (EPI == 2) {
          const long idx = (long)z * zsC + m * (long)N + n;
          outF[idx] = val + aux0[idx];
        } else if constexpr (EPI == 3) {
          const float t = val + aux0[n];
          const float gl = 0.5f * t * (1.0f + erff(t * 0.70710678118654752f));
          outU[m * (long)N + n] = f2bf(gl);
        } else if constexpr (EPI == 4) {
          outF[m * (long)N + n] = val + aux0[n] + aux1[m * (long)N + n];
        } else {
          outU[m * (long)N + n] = f2bf(val);
        }
      }
    }
  }
}

// ---------------------------------------------------------------------------
// LayerNorm over D=1024, one wave per row, 4 rows/block.
// SPLIT2: write [row][2048] = [hi | lo]; else [row][1024] plain bf16.
// ---------------------------------------------------------------------------
template <bool SPLIT2>
__global__ __launch_bounds__(256) void ln_k(const float* __restrict__ x,
                                            const float* __restrict__ gw,
                                            const float* __restrict__ bw,
                                            u16* __restrict__ out) {
  const int lane = threadIdx.x & 63;
  const int wv = threadIdx.x >> 6;
  const long row = (long)blockIdx.x * 4 + wv;
  const float* xr = x + row * 1024;
  float4 v[4];
  float s = 0.f, ss = 0.f;
#pragma unroll
  for (int j = 0; j < 4; ++j) {
    v[j] = *(const float4*)(xr + (lane + 64 * j) * 4);
    s += v[j].x + v[j].y + v[j].z + v[j].w;
    ss += v[j].x * v[j].x + v[j].y * v[j].y + v[j].z * v[j].z + v[j].w * v[j].w;
  }
#pragma unroll
  for (int o = 32; o; o >>= 1) {
    s += __shfl_xor(s, o);
    ss += __shfl_xor(ss, o);
  }
  const float mu = s * (1.f / 1024.f);
  const float var = ss * (1.f / 1024.f) - mu * mu;
  const float rs = rsqrtf(var + 1e-5f);
  u16* orow = out + row * (SPLIT2 ? 2048 : 1024);
#pragma unroll
  for (int j = 0; j < 4; ++j) {
    const int n = (lane + 64 * j) * 4;
    const float4 gg = *(const float4*)(gw + n);
    const float4 bb = *(const float4*)(bw + n);
    const float y[4] = {(v[j].x - mu) * rs * gg.x + bb.x,
                        (v[j].y - mu) * rs * gg.y + bb.y,
                        (v[j].z - mu) * rs * gg.z + bb.z,
                        (v[j].w - mu) * rs * gg.w + bb.w};
    u16x4 H, L;
#pragma unroll
    for (int c = 0; c < 4; ++c) {
      u16 hi, lo;
      splitbf(y[c], hi, lo);
      H[c] = hi;
      L[c] = lo;
    }
    if constexpr (SPLIT2) {
      *(u16x4*)(orow + n) = H;
      *(u16x4*)(orow + 1024 + n) = L;
    } else {
      *(u16x4*)(orow + n) = H;
    }
  }
}

// ---------------------------------------------------------------------------
// Tiled transpose+convert. in [R,C] -> out [C,R] (per z).
// MODE 0: f32 -> bf16; MODE 2: bf16 -> bf16;
// MODE 3 (w_qkv): f32 [1024,3072] -> cols<2048: wq2 [c][hi|lo] (ld 2048);
//                 cols>=2048: wv [c-2048][1024] bf16.
// ---------------------------------------------------------------------------
template <int MODE>
__global__ __launch_bounds__(256) void transpose_k(const void* __restrict__ in,
                                                   u16* __restrict__ out,
                                                   u16* __restrict__ out2,
                                                   int R, int C, long zsIn,
                                                   long zsOut) {
  __shared__ float tile[32][33];
  const int z = blockIdx.z;
  const int c0 = blockIdx.x * 32, r0 = blockIdx.y * 32;
#pragma unroll
  for (int i = 0; i < 4; ++i) {
    const int lin = threadIdx.x + 256 * i;
    const int rr = lin >> 5, cc = lin & 31;
    float vv;
    if constexpr (MODE == 2)
      vv = bf2f(((const u16*)in + (long)z * zsIn)[(long)(r0 + rr) * C + c0 + cc]);
    else
      vv = ((const float*)in)[(long)(r0 + rr) * C + c0 + cc];
    tile[rr][cc] = vv;
  }
  __syncthreads();
  u16* outz = out + (long)z * zsOut;
#pragma unroll
  for (int i = 0; i < 4; ++i) {
    const int lin = threadIdx.x + 256 * i;
    const int oc = lin >> 5, orr = lin & 31;
    const float vv = tile[orr][oc];
    const int c = c0 + oc;
    if constexpr (MODE == 3) {
      if (c < 2048) {
        u16 hi, lo;
        splitbf(vv, hi, lo);
        u16* p = out + (long)c * 2048 + (r0 + orr);
        p[0] = hi;
        p[1024] = lo;
      } else {
        out2[(long)(c - 2048) * 1024 + (r0 + orr)] = f2bf(vv);
      }
    } else {
      outz[(long)c * R + (r0 + orr)] = f2bf(vv);
    }
  }
}

// ---------------------------------------------------------------------------
// Row softmax over 2048 cols, f32 in -> bf16 out IN-PLACE (P overwrites the
// first 4 KB of each 16 KB score row; all reads precede first barrier).
// ---------------------------------------------------------------------------
__global__ __launch_bounds__(256) void softmax_k(float* __restrict__ S) {
  const long row = blockIdx.x;
  float* sr = S + row * 2048;
  u16* pr = (u16*)sr;
  const int tid = threadIdx.x;
  const int lane = tid & 63, wv = tid >> 6;
  __shared__ float red[8];
  const float4 v0 = *(const float4*)(sr + tid * 4);
  const float4 v1 = *(const float4*)(sr + 1024 + tid * 4);
  float mx = fmaxf(fmaxf(fmaxf(v0.x, v0.y), fmaxf(v0.z, v0.w)),
                   fmaxf(fmaxf(v1.x, v1.y), fmaxf(v1.z, v1.w)));
#pragma unroll
  for (int o = 32; o; o >>= 1) mx = fmaxf(mx, __shfl_xor(mx, o));
  if (lane == 0) red[wv] = mx;
  __syncthreads();
  mx = fmaxf(fmaxf(red[0], red[1]), fmaxf(red[2], red[3]));
  float e[8];
  e[0] = expf(v0.x - mx); e[1] = expf(v0.y - mx);
  e[2] = expf(v0.z - mx); e[3] = expf(v0.w - mx);
  e[4] = expf(v1.x - mx); e[5] = expf(v1.y - mx);
  e[6] = expf(v1.z - mx); e[7] = expf(v1.w - mx);
  float sm = e[0] + e[1] + e[2] + e[3] + e[4] + e[5] + e[6] + e[7];
#pragma unroll
  for (int o = 32; o; o >>= 1) sm += __shfl_xor(sm, o);
  if (lane == 0) red[4 + wv] = sm;
  __syncthreads();
  sm = red[4] + red[5] + red[6] + red[7];
  const float inv = 1.f / sm;
  u16x4 a, b;
  a[0] = f2bf(e[0] * inv); a[1] = f2bf(e[1] * inv);
  a[2] = f2bf(e[2] * inv); a[3] = f2bf(e[3] * inv);
  b[0] = f2bf(e[4] * inv); b[1] = f2bf(e[5] * inv);
  b[2] = f2bf(e[6] * inv); b[3] = f2bf(e[7] * inv);
  *(u16x4*)(pr + tid * 4) = a;
  *(u16x4*)(pr + 1024 + tid * 4) = b;
}

// ---------------------------------------------------------------------------
extern "C" void kernel_launch(void* const* d_in, const int* in_sizes, int n_in,
                              void* d_out, int out_size, void* d_ws,
                              size_t ws_size, hipStream_t stream) {
  const float* x     = (const float*)d_in[0];  // [4,2048,1024]
  const float* w_qkv = (const float*)d_in[1];  // [1024,3072]
  const float* fc1_w = (const float*)d_in[2];  // [1024,4096]
  const float* fc1_b = (const float*)d_in[3];  // [4096]
  const float* fc2_w = (const float*)d_in[4];  // [4096,1024]
  const float* fc2_b = (const float*)d_in[5];  // [1024]
  const float* ln1_g = (const float*)d_in[6];
  const float* ln1_b = (const float*)d_in[7];
  const float* ln2_g = (const float*)d_in[8];
  const float* ln2_b = (const float*)d_in[9];
  float* out = (float*)d_out;

  // workspace (peak 160 MB, phase-aliased)
  char* ws = (char*)d_ws;
  const long MB = 1024L * 1024L;
  u16*   q2  = (u16*)(ws + 0);         // 32MB [8192,2048] (qh|ql)
  u16*   k2  = (u16*)(ws + 32 * MB);   // 32MB [8192,2048] (kh|kl)
  u16*   vbuf= (u16*)(ws + 64 * MB);   // 16MB [8192,1024]
  u16*   vT  = (u16*)(ws + 80 * MB);   // 16MB [4][1024][2048]
  u16*   h2w = (u16*)(ws + 96 * MB);   // 32MB [8192,2048] (hh|hl)
  float* sc  = (float*)(ws + 96 * MB); // 64MB scores (h2w/wq2/wv dead)
  u16*   wq2 = (u16*)(ws + 128 * MB);  //  8MB [2048,2048] (wh|wl)
  u16*   wv  = (u16*)(ws + 136 * MB);  //  2MB [1024,1024]
  float* r2  = (float*)(ws + 0);       // 32MB (q2 dead)
  u16*   h2  = (u16*)(ws + 32 * MB);   // 16MB (k2 dead)
  u16*   w1T = (u16*)(ws + 48 * MB);   //  8MB [4096,1024]
  u16*   w2T = (u16*)(ws + 56 * MB);   //  8MB [1024,4096]
  u16*   g   = (u16*)(ws + 64 * MB);   // 64MB [8192,4096] (vbuf..sc dead)

  dim3 blk(256);
  dim3 blk8(512);
  const int LDS4 = 131072;  // JF=4: 2 x (32KB A + 32KB B)
  const int LDS2 = 98304;   // JF=2: 2 x (32KB A + 16KB B)
  (void)hipFuncSetAttribute((const void*)gemm8<4, 4, 0, true, true>,
                            hipFuncAttributeMaxDynamicSharedMemorySize, LDS4);
  (void)hipFuncSetAttribute((const void*)gemm8<2, 2, 5, false, true>,
                            hipFuncAttributeMaxDynamicSharedMemorySize, LDS2);
  (void)hipFuncSetAttribute((const void*)gemm8<4, 4, 1, true, false>,
                            hipFuncAttributeMaxDynamicSharedMemorySize, LDS4);
  (void)hipFuncSetAttribute((const void*)gemm8<2, 2, 2, false, false>,
                            hipFuncAttributeMaxDynamicSharedMemorySize, LDS2);
  (void)hipFuncSetAttribute((const void*)gemm8<4, 4, 3, false, true>,
                            hipFuncAttributeMaxDynamicSharedMemorySize, LDS4);
  (void)hipFuncSetAttribute((const void*)gemm8<2, 2, 4, false, true>,
                            hipFuncAttributeMaxDynamicSharedMemorySize, LDS2);

  // 1) LN1 -> h2w [hi|lo]
  ln_k<true><<<2048, blk, 0, stream>>>(x, ln1_g, ln1_b, h2w);
  // 2) w_qkv -> wq2 (cols<2048, split) + wv (v cols, bf16)
  transpose_k<3><<<dim3(3072 / 32, 1024 / 32, 1), blk, 0, stream>>>(
      w_qkv, wq2, wv, 1024, 3072, 0, 0);
  // 3) qk-GEMM (emulated fp32, K=3072 tripled): -> q2, k2.  grid 256 exact.
  gemm8<4, 4, 0, true, true><<<dim3(8, 32, 1), blk8, LDS4, stream>>>(
      h2w, wq2, 8192, 2048, 3072, 2048, 2048, 0, 0, 0, nullptr, q2, k2,
      nullptr, nullptr);
  // 4) v-GEMM (plain bf16, K=1024): -> vbuf.  grid 256 exact.
  gemm8<2, 2, 5, false, true><<<dim3(8, 32, 1), blk8, LDS2, stream>>>(
      h2w, wv, 8192, 1024, 1024, 2048, 1024, 0, 0, 0, nullptr, vbuf, nullptr,
      nullptr, nullptr);
  // 5) v -> vT per batch
  transpose_k<2><<<dim3(1024 / 32, 2048 / 32, 4), blk, 0, stream>>>(
      vbuf, vT, nullptr, 2048, 1024, 2048L * 1024, 1024L * 2048);
  // 6) GEMM2 (emulated fp32, K=3072 tripled): scores.  grid 256 exact.
  gemm8<4, 4, 1, true, false><<<dim3(8, 8, 4), blk8, LDS4, stream>>>(
      q2, k2, 2048, 2048, 3072, 2048, 2048, 2048L * 2048, 2048L * 2048,
      2048L * 2048, sc, nullptr, nullptr, nullptr, nullptr);
  // 7) softmax in-place: P (bf16, lda=4096 u16) overwrites score rows
  softmax_k<<<8192, blk, 0, stream>>>(sc);
  // 8) GEMM3: attn = P @ vT + resid.  grid 256 exact.
  gemm8<2, 2, 2, false, false><<<dim3(8, 8, 4), blk8, LDS2, stream>>>(
      (const u16*)sc, vT, 2048, 1024, 2048, 4096, 2048, 2048L * 4096,
      1024L * 2048, 2048L * 1024, r2, nullptr, nullptr, x, nullptr);
  // 9) LN2 -> h2 bf16
  ln_k<false><<<2048, blk, 0, stream>>>(r2, ln2_g, ln2_b, h2);
  // 10) fc1_w -> w1T, fc2_w -> w2T
  transpose_k<0><<<dim3(4096 / 32, 1024 / 32, 1), blk, 0, stream>>>(
      fc1_w, w1T, nullptr, 1024, 4096, 0, 0);
  transpose_k<0><<<dim3(1024 / 32, 4096 / 32, 1), blk, 0, stream>>>(
      fc2_w, w2T, nullptr, 4096, 1024, 0, 0);
  // 11) GEMM4: g = gelu(h2 @ fc1_w + b1).  grid 512 = 2 exact waves.
  gemm8<4, 4, 3, false, true><<<dim3(16, 32, 1), blk8, LDS4, stream>>>(
      h2, w1T, 8192, 4096, 1024, 1024, 1024, 0, 0, 0, nullptr, g, nullptr,
      fc1_b, nullptr);
  // 12) GEMM5: out = g @ fc2_w + b2 + r2.  grid 256 exact.
  gemm8<2, 2, 4, false, true><<<dim3(8, 32, 1), blk8, LDS2, stream>>>(
      g, w2T, 8192, 1024, 4096, 4096, 4096, 0, 0, 0, out, nullptr, nullptr,
      fc2_b, r2);
}

// Round 4
// 517.037 us; speedup vs baseline: 1.1709x; 1.0213x over previous
//
#include <hip/hip_runtime.h>
#include <math.h>

typedef unsigned short u16;
typedef unsigned int u32;
typedef short s16x8 __attribute__((ext_vector_type(8)));
typedef float f32x4 __attribute__((ext_vector_type(4)));
typedef u16 u16x4 __attribute__((ext_vector_type(4)));

__device__ __forceinline__ u16 f2bf(float x) {
  u32 u = __float_as_uint(x);
  u32 r = u + 0x7FFFu + ((u >> 16) & 1u);  // round-to-nearest-even
  return (u16)(r >> 16);
}
__device__ __forceinline__ float bf2f(u16 h) {
  return __uint_as_float(((u32)h) << 16);
}
__device__ __forceinline__ void splitbf(float x, u16 &hi, u16 &lo) {
  hi = f2bf(x);
  lo = f2bf(x - bf2f(hi));
}

__device__ __forceinline__ void gload16(const void* g, void* l) {
  __builtin_amdgcn_global_load_lds(
      (const __attribute__((address_space(1))) void*)g,
      (__attribute__((address_space(3))) void*)l, 16, 0, 0);
}

// ---------------------------------------------------------------------------
// 8-phase NT GEMM (m201-style), round-4: all K-loop addresses hoisted.
// A [M,lda] rm, B [N,ldb] rm, C[m][n] = sum_k A[m][k]*B[n][k] over logical K
// (TRIPLE: K=3072 maps into 2048-wide [hi|lo] storage: A=(hi,lo,hi)
// ktA=kt<32?kt:kt-32, B=(hi,hi,lo) ktB=kt<16?kt:kt-16).
// Tile 256 x (64*JF), BK=64, 8 waves (2Mx4N), mfma_f32_16x16x32_bf16.
// LDS offsets collapse to linear form: off(row) = row*128 (halves contiguous),
// slot0 = kgrp ^ (fr&7) thread-invariant, kk=1 base = kk=0 base ^ 64.
// => ds_read = per-tile base + compile-time offset imm (zero per-read VALU).
// Staging: 4 precomputed 64-bit lane bases + uniform ktm*64 add.
// Schedule identical to round 3 (verified): per tile s (cur=s&1):
//   p0: read A-frags(+all B); stageA.h0(s+1)->buf[cur^1]
//   p1: stageA.h1(s+1); stageB.h0(s+2)->buf[cur]
//   p2 (JF4): stageB.h1(s+2)
//   last: counted vmcnt(JF) -> drains exactly tile s+1, B(s+2) in flight.
// EPI: 0=qk split2, 1=scores f32, 2=+resid f32, 3=+bias+gelu->bf16,
//      4=+bias+resid->f32, 5=plain bf16
// ---------------------------------------------------------------------------
template <int JF, int NPH, int EPI, bool TRIPLE, bool SWZ>
__global__ __launch_bounds__(512, 2) void gemm8(
    const u16* __restrict__ A, const u16* __restrict__ B, int M, int N, int K,
    int lda, int ldb, long zsA, long zsB, long zsC, float* __restrict__ outF,
    u16* __restrict__ outU, u16* __restrict__ outU2,
    const float* __restrict__ aux0, const float* __restrict__ aux1) {
  constexpr int BUF = 32768 + JF * 8192;  // bytes per double-buffer half
  constexpr int IPP = 8 / NPH;            // i-frags per phase
  extern __shared__ __align__(16) char smem[];

  const int tid = threadIdx.x;
  const int lane = tid & 63;
  const int wave = tid >> 6;
  const int z = blockIdx.z;

  int bx = blockIdx.x, by = blockIdx.y;
  if constexpr (SWZ) {
    const int gx = gridDim.x;
    const int nwg = gx * gridDim.y;
    const int id = by * gx + bx;
    const int q = nwg >> 3;  // nwg % 8 == 0 for all our grids
    const int id2 = (id & 7) * q + (id >> 3);
    bx = id2 % gx;
    by = id2 / gx;
  }
  const long row0 = (long)by * 256;
  const long col0 = (long)bx * (64 * JF);

  const u16* __restrict__ Ab = A + (long)z * zsA;
  const u16* __restrict__ Bb = B + (long)z * zsB;

  // staging lane geometry (pre-swizzled global slot, linear LDS dest)
  const int srow = lane >> 3;
  const int gslot = (lane & 7) ^ srow;
  // fragment lane geometry
  const int fr = lane & 15;
  const int kgrp = lane >> 4;
  const int wm = (wave >> 2) << 7;        // 0 or 128
  const int wn = (wave & 3) * (16 * JF);

  const int nk = K >> 6;

  // ---- hoisted LDS read bases (byte offsets; kk=1 = kk=0 ^ 64, carry-free)
  const int slot0 = kgrp ^ (fr & 7);
  const int offA0 = (wm + fr) * 128 + slot0 * 16;
  const int offA1 = offA0 ^ 64;
  const int offB0 = 32768 + (wn + fr) * 128 + slot0 * 16;
  const int offB1 = offB0 ^ 64;

  // ---- hoisted staging bases
  const u16* const gA0 = Ab + (row0 + wave * 16 + srow) * (long)lda + gslot * 8;
  const u16* const gA1 = gA0 + 128 * (long)lda;
  const u16* const gB0 = Bb + (col0 + wave * 16 + srow) * (long)ldb + gslot * 8;
  const u16* const gB1 = gB0 + 128 * (long)ldb;
  char* const dA = smem + wave * 2048 + lane * 16;
  char* const dB = dA + 32768;

  f32x4 acc[8][JF] = {};
  s16x8 bfrag[2][JF];

  auto stageA = [&](int buf, int kt, int h) {
    const int ktm = TRIPLE ? (kt < 32 ? kt : kt - 32) : kt;
    const long ko = (long)ktm * 64;
    const u16* g = (h ? gA1 : gA0) + ko;
    char* d = dA + buf * BUF + (h ? 16384 : 0);
    gload16(g, d);
    gload16(g + 8 * (long)lda, d + 1024);
  };
  auto stageB = [&](int buf, int kt, int h) {
    const int ktm = TRIPLE ? (kt < 16 ? kt : kt - 16) : kt;
    const long ko = (long)ktm * 64;
    const u16* g = (h ? gB1 : gB0) + ko;
    char* d = dB + buf * BUF + (h ? 16384 : 0);
    gload16(g, d);
    gload16(g + 8 * (long)ldb, d + 1024);
  };

  // prologue: tile0 (A+B) -> buf0; tile1's B -> buf1.  Drain tile0 only.
  stageA(0, 0, 0);
  stageA(0, 0, 1);
  stageB(0, 0, 0);
  if constexpr (JF == 4) stageB(0, 0, 1);
  stageB(1, 1, 0);
  if constexpr (JF == 4) stageB(1, 1, 1);
  if constexpr (JF == 4)
    asm volatile("s_waitcnt vmcnt(4)");
  else
    asm volatile("s_waitcnt vmcnt(2)");
  __builtin_amdgcn_s_barrier();

  for (int s = 0; s < nk; ++s) {
    const int cur = s & 1;
    const bool stA = (s + 1 < nk);
    const bool stB = (s + 2 < nk);
    // per-tile LDS read bases (4 adds per tile, then offset-imm reads)
    const char* sb = smem + cur * BUF;
    const char* pA0 = sb + offA0;
    const char* pA1 = sb + offA1;
    const char* pB0 = sb + offB0;
    const char* pB1 = sb + offB1;
#pragma unroll
    for (int p = 0; p < NPH; ++p) {
      s16x8 af[IPP][2];
#pragma unroll
      for (int ii = 0; ii < IPP; ++ii) {
        af[ii][0] = *(const s16x8*)(pA0 + (p * IPP + ii) * 2048);
        af[ii][1] = *(const s16x8*)(pA1 + (p * IPP + ii) * 2048);
      }
      if (p == 0) {
#pragma unroll
        for (int j = 0; j < JF; ++j) {
          bfrag[0][j] = *(const s16x8*)(pB0 + j * 2048);
          bfrag[1][j] = *(const s16x8*)(pB1 + j * 2048);
        }
      }
      // staging map
      if (p == 0 && stA) stageA(cur ^ 1, s + 1, 0);
      if (p == 1) {
        if (stA) stageA(cur ^ 1, s + 1, 1);
        if (stB) stageB(cur, s + 2, 0);
      }
      if constexpr (NPH == 4) {
        if (p == 2 && stB) stageB(cur, s + 2, 1);
      }
      __builtin_amdgcn_s_barrier();
      asm volatile("s_waitcnt lgkmcnt(0)");
      __builtin_amdgcn_s_setprio(1);
#pragma unroll
      for (int kk = 0; kk < 2; ++kk)
#pragma unroll
        for (int ii = 0; ii < IPP; ++ii)
#pragma unroll
          for (int j = 0; j < JF; ++j)
            acc[p * IPP + ii][j] = __builtin_amdgcn_mfma_f32_16x16x32_bf16(
                af[ii][kk], bfrag[kk][j], acc[p * IPP + ii][j], 0, 0, 0);
      __builtin_amdgcn_s_setprio(0);
      if (p == NPH - 1) {
        if (stB) {
          if constexpr (JF == 4)
            asm volatile("s_waitcnt vmcnt(4)");
          else
            asm volatile("s_waitcnt vmcnt(2)");
        } else {
          asm volatile("s_waitcnt vmcnt(0)");
        }
      }
      __builtin_amdgcn_s_barrier();
    }
  }

  // epilogue: C/D frag layout: col = lane&15 (fr), row = kgrp*4 + r
#pragma unroll
  for (int i = 0; i < 8; ++i) {
#pragma unroll
    for (int j = 0; j < JF; ++j) {
#pragma unroll
      for (int r = 0; r < 4; ++r) {
        const long m = row0 + wm + i * 16 + (kgrp << 2) + r;
        const long n = col0 + wn + j * 16 + fr;
        const float val = acc[i][j][r];
        if constexpr (EPI == 0) {
          // qk: n<1024 -> q2 [hi|lo]; else k2 [hi|lo]
          u16 hi, lo;
          splitbf(val, hi, lo);
          if (n < 1024) {
            u16* p = outU + m * 2048 + n;
            p[0] = hi;
            p[1024] = lo;
          } else {
            u16* p = outU2 + m * 2048 + (n - 1024);
            p[0] = hi;
            p[1024] = lo;
          }
        } else if constexpr (EPI == 1) {
          outF[(long)z * zsC + m * (long)N + n] = val;
        } else if constexpr (EPI == 2) {
          const long idx = (long)z * zsC + m * (long)N + n;
          outF[idx] = val + aux0[idx];
        } else if constexpr (EPI == 3) {
          const float t = val + aux0[n];
          const float gl = 0.5f * t * (1.0f + erff(t * 0.70710678118654752f));
          outU[m * (long)N + n] = f2bf(gl);
        } else if constexpr (EPI == 4) {
          outF[m * (long)N + n] = val + aux0[n] + aux1[m * (long)N + n];
        } else {
          outU[m * (long)N + n] = f2bf(val);
        }
      }
    }
  }
}

// ---------------------------------------------------------------------------
// LayerNorm over D=1024, one wave per row, 4 rows/block.
// SPLIT2: write [row][2048] = [hi | lo]; else [row][1024] plain bf16.
// ---------------------------------------------------------------------------
template <bool SPLIT2>
__global__ __launch_bounds__(256) void ln_k(const float* __restrict__ x,
                                            const float* __restrict__ gw,
                                            const float* __restrict__ bw,
                                            u16* __restrict__ out) {
  const int lane = threadIdx.x & 63;
  const int wv = threadIdx.x >> 6;
  const long row = (long)blockIdx.x * 4 + wv;
  const float* xr = x + row * 1024;
  float4 v[4];
  float s = 0.f, ss = 0.f;
#pragma unroll
  for (int j = 0; j < 4; ++j) {
    v[j] = *(const float4*)(xr + (lane + 64 * j) * 4);
    s += v[j].x + v[j].y + v[j].z + v[j].w;
    ss += v[j].x * v[j].x + v[j].y * v[j].y + v[j].z * v[j].z + v[j].w * v[j].w;
  }
#pragma unroll
  for (int o = 32; o; o >>= 1) {
    s += __shfl_xor(s, o);
    ss += __shfl_xor(ss, o);
  }
  const float mu = s * (1.f / 1024.f);
  const float var = ss * (1.f / 1024.f) - mu * mu;
  const float rs = rsqrtf(var + 1e-5f);
  u16* orow = out + row * (SPLIT2 ? 2048 : 1024);
#pragma unroll
  for (int j = 0; j < 4; ++j) {
    const int n = (lane + 64 * j) * 4;
    const float4 gg = *(const float4*)(gw + n);
    const float4 bb = *(const float4*)(bw + n);
    const float y[4] = {(v[j].x - mu) * rs * gg.x + bb.x,
                        (v[j].y - mu) * rs * gg.y + bb.y,
                        (v[j].z - mu) * rs * gg.z + bb.z,
                        (v[j].w - mu) * rs * gg.w + bb.w};
    u16x4 H, L;
#pragma unroll
    for (int c = 0; c < 4; ++c) {
      u16 hi, lo;
      splitbf(y[c], hi, lo);
      H[c] = hi;
      L[c] = lo;
    }
    if constexpr (SPLIT2) {
      *(u16x4*)(orow + n) = H;
      *(u16x4*)(orow + 1024 + n) = L;
    } else {
      *(u16x4*)(orow + n) = H;
    }
  }
}

// ---------------------------------------------------------------------------
// Tiled transpose+convert. in [R,C] -> out [C,R] (per z).
// MODE 0: f32 -> bf16; MODE 2: bf16 -> bf16;
// MODE 3 (w_qkv): f32 [1024,3072] -> cols<2048: wq2 [c][hi|lo] (ld 2048);
//                 cols>=2048: wv [c-2048][1024] bf16.
// ---------------------------------------------------------------------------
template <int MODE>
__global__ __launch_bounds__(256) void transpose_k(const void* __restrict__ in,
                                                   u16* __restrict__ out,
                                                   u16* __restrict__ out2,
                                                   int R, int C, long zsIn,
                                                   long zsOut) {
  __shared__ float tile[32][33];
  const int z = blockIdx.z;
  const int c0 = blockIdx.x * 32, r0 = blockIdx.y * 32;
#pragma unroll
  for (int i = 0; i < 4; ++i) {
    const int lin = threadIdx.x + 256 * i;
    const int rr = lin >> 5, cc = lin & 31;
    float vv;
    if constexpr (MODE == 2)
      vv = bf2f(((const u16*)in + (long)z * zsIn)[(long)(r0 + rr) * C + c0 + cc]);
    else
      vv = ((const float*)in)[(long)(r0 + rr) * C + c0 + cc];
    tile[rr][cc] = vv;
  }
  __syncthreads();
  u16* outz = out + (long)z * zsOut;
#pragma unroll
  for (int i = 0; i < 4; ++i) {
    const int lin = threadIdx.x + 256 * i;
    const int oc = lin >> 5, orr = lin & 31;
    const float vv = tile[orr][oc];
    const int c = c0 + oc;
    if constexpr (MODE == 3) {
      if (c < 2048) {
        u16 hi, lo;
        splitbf(vv, hi, lo);
        u16* p = out + (long)c * 2048 + (r0 + orr);
        p[0] = hi;
        p[1024] = lo;
      } else {
        out2[(long)(c - 2048) * 1024 + (r0 + orr)] = f2bf(vv);
      }
    } else {
      outz[(long)c * R + (r0 + orr)] = f2bf(vv);
    }
  }
}

// ---------------------------------------------------------------------------
// Row softmax over 2048 cols, f32 in -> bf16 out IN-PLACE (P overwrites the
// first 4 KB of each 16 KB score row; all reads precede first barrier).
// ---------------------------------------------------------------------------
__global__ __launch_bounds__(256) void softmax_k(float* __restrict__ S) {
  const long row = blockIdx.x;
  float* sr = S + row * 2048;
  u16* pr = (u16*)sr;
  const int tid = threadIdx.x;
  const int lane = tid & 63, wv = tid >> 6;
  __shared__ float red[8];
  const float4 v0 = *(const float4*)(sr + tid * 4);
  const float4 v1 = *(const float4*)(sr + 1024 + tid * 4);
  float mx = fmaxf(fmaxf(fmaxf(v0.x, v0.y), fmaxf(v0.z, v0.w)),
                   fmaxf(fmaxf(v1.x, v1.y), fmaxf(v1.z, v1.w)));
#pragma unroll
  for (int o = 32; o; o >>= 1) mx = fmaxf(mx, __shfl_xor(mx, o));
  if (lane == 0) red[wv] = mx;
  __syncthreads();
  mx = fmaxf(fmaxf(red[0], red[1]), fmaxf(red[2], red[3]));
  float e[8];
  e[0] = expf(v0.x - mx); e[1] = expf(v0.y - mx);
  e[2] = expf(v0.z - mx); e[3] = expf(v0.w - mx);
  e[4] = expf(v1.x - mx); e[5] = expf(v1.y - mx);
  e[6] = expf(v1.z - mx); e[7] = expf(v1.w - mx);
  float sm = e[0] + e[1] + e[2] + e[3] + e[4] + e[5] + e[6] + e[7];
#pragma unroll
  for (int o = 32; o; o >>= 1) sm += __shfl_xor(sm, o);
  if (lane == 0) red[4 + wv] = sm;
  __syncthreads();
  sm = red[4] + red[5] + red[6] + red[7];
  const float inv = 1.f / sm;
  u16x4 a, b;
  a[0] = f2bf(e[0] * inv); a[1] = f2bf(e[1] * inv);
  a[2] = f2bf(e[2] * inv); a[3] = f2bf(e[3] * inv);
  b[0] = f2bf(e[4] * inv); b[1] = f2bf(e[5] * inv);
  b[2] = f2bf(e[6] * inv); b[3] = f2bf(e[7] * inv);
  *(u16x4*)(pr + tid * 4) = a;
  *(u16x4*)(pr + 1024 + tid * 4) = b;
}

// ---------------------------------------------------------------------------
extern "C" void kernel_launch(void* const* d_in, const int* in_sizes, int n_in,
                              void* d_out, int out_size, void* d_ws,
                              size_t ws_size, hipStream_t stream) {
  const float* x     = (const float*)d_in[0];  // [4,2048,1024]
  const float* w_qkv = (const float*)d_in[1];  // [1024,3072]
  const float* fc1_w = (const float*)d_in[2];  // [1024,4096]
  const float* fc1_b = (const float*)d_in[3];  // [4096]
  const float* fc2_w = (const float*)d_in[4];  // [4096,1024]
  const float* fc2_b = (const float*)d_in[5];  // [1024]
  const float* ln1_g = (const float*)d_in[6];
  const float* ln1_b = (const float*)d_in[7];
  const float* ln2_g = (const float*)d_in[8];
  const float* ln2_b = (const float*)d_in[9];
  float* out = (float*)d_out;

  // workspace (peak 160 MB, phase-aliased)
  char* ws = (char*)d_ws;
  const long MB = 1024L * 1024L;
  u16*   q2  = (u16*)(ws + 0);         // 32MB [8192,2048] (qh|ql)
  u16*   k2  = (u16*)(ws + 32 * MB);   // 32MB [8192,2048] (kh|kl)
  u16*   vbuf= (u16*)(ws + 64 * MB);   // 16MB [8192,1024]
  u16*   vT  = (u16*)(ws + 80 * MB);   // 16MB [4][1024][2048]
  u16*   h2w = (u16*)(ws + 96 * MB);   // 32MB [8192,2048] (hh|hl)
  float* sc  = (float*)(ws + 96 * MB); // 64MB scores (h2w/wq2/wv dead)
  u16*   wq2 = (u16*)(ws + 128 * MB);  //  8MB [2048,2048] (wh|wl)
  u16*   wv  = (u16*)(ws + 136 * MB);  //  2MB [1024,1024]
  float* r2  = (float*)(ws + 0);       // 32MB (q2 dead)
  u16*   h2  = (u16*)(ws + 32 * MB);   // 16MB (k2 dead)
  u16*   w1T = (u16*)(ws + 48 * MB);   //  8MB [4096,1024]
  u16*   w2T = (u16*)(ws + 56 * MB);   //  8MB [1024,4096]
  u16*   g   = (u16*)(ws + 64 * MB);   // 64MB [8192,4096] (vbuf..sc dead)

  dim3 blk(256);
  dim3 blk8(512);
  const int LDS4 = 131072;  // JF=4: 2 x (32KB A + 32KB B)
  const int LDS2 = 98304;   // JF=2: 2 x (32KB A + 16KB B)
  (void)hipFuncSetAttribute((const void*)gemm8<4, 4, 0, true, true>,
                            hipFuncAttributeMaxDynamicSharedMemorySize, LDS4);
  (void)hipFuncSetAttribute((const void*)gemm8<2, 2, 5, false, true>,
                            hipFuncAttributeMaxDynamicSharedMemorySize, LDS2);
  (void)hipFuncSetAttribute((const void*)gemm8<4, 4, 1, true, true>,
                            hipFuncAttributeMaxDynamicSharedMemorySize, LDS4);
  (void)hipFuncSetAttribute((const void*)gemm8<2, 2, 2, false, true>,
                            hipFuncAttributeMaxDynamicSharedMemorySize, LDS2);
  (void)hipFuncSetAttribute((const void*)gemm8<4, 4, 3, false, true>,
                            hipFuncAttributeMaxDynamicSharedMemorySize, LDS4);
  (void)hipFuncSetAttribute((const void*)gemm8<2, 2, 4, false, true>,
                            hipFuncAttributeMaxDynamicSharedMemorySize, LDS2);

  // 1) LN1 -> h2w [hi|lo]
  ln_k<true><<<2048, blk, 0, stream>>>(x, ln1_g, ln1_b, h2w);
  // 2) w_qkv -> wq2 (cols<2048, split) + wv (v cols, bf16)
  transpose_k<3><<<dim3(3072 / 32, 1024 / 32, 1), blk, 0, stream>>>(
      w_qkv, wq2, wv, 1024, 3072, 0, 0);
  // 3) qk-GEMM (emulated fp32, K=3072 tripled): -> q2, k2.  grid 256 exact.
  gemm8<4, 4, 0, true, true><<<dim3(8, 32, 1), blk8, LDS4, stream>>>(
      h2w, wq2, 8192, 2048, 3072, 2048, 2048, 0, 0, 0, nullptr, q2, k2,
      nullptr, nullptr);
  // 4) v-GEMM (plain bf16, K=1024): -> vbuf.  grid 256 exact.
  gemm8<2, 2, 5, false, true><<<dim3(8, 32, 1), blk8, LDS2, stream>>>(
      h2w, wv, 8192, 1024, 1024, 2048, 1024, 0, 0, 0, nullptr, vbuf, nullptr,
      nullptr, nullptr);
  // 5) v -> vT per batch
  transpose_k<2><<<dim3(1024 / 32, 2048 / 32, 4), blk, 0, stream>>>(
      vbuf, vT, nullptr, 2048, 1024, 2048L * 1024, 1024L * 2048);
  // 6) GEMM2 (emulated fp32, K=3072 tripled): scores.  grid 64/z, 64%8==0.
  gemm8<4, 4, 1, true, true><<<dim3(8, 8, 4), blk8, LDS4, stream>>>(
      q2, k2, 2048, 2048, 3072, 2048, 2048, 2048L * 2048, 2048L * 2048,
      2048L * 2048, sc, nullptr, nullptr, nullptr, nullptr);
  // 7) softmax in-place: P (bf16, lda=4096 u16) overwrites score rows
  softmax_k<<<8192, blk, 0, stream>>>(sc);
  // 8) GEMM3: attn = P @ vT + resid.  grid 256 exact.
  gemm8<2, 2, 2, false, true><<<dim3(8, 8, 4), blk8, LDS2, stream>>>(
      (const u16*)sc, vT, 2048, 1024, 2048, 4096, 2048, 2048L * 4096,
      1024L * 2048, 2048L * 1024, r2, nullptr, nullptr, x, nullptr);
  // 9) LN2 -> h2 bf16
  ln_k<false><<<2048, blk, 0, stream>>>(r2, ln2_g, ln2_b, h2);
  // 10) fc1_w -> w1T, fc2_w -> w2T
  transpose_k<0><<<dim3(4096 / 32, 1024 / 32, 1), blk, 0, stream>>>(
      fc1_w, w1T, nullptr, 1024, 4096, 0, 0);
  transpose_k<0><<<dim3(1024 / 32, 4096 / 32, 1), blk, 0, stream>>>(
      fc2_w, w2T, nullptr, 4096, 1024, 0, 0);
  // 11) GEMM4: g = gelu(h2 @ fc1_w + b1).  grid 512 = 2 exact waves.
  gemm8<4, 4, 3, false, true><<<dim3(16, 32, 1), blk8, LDS4, stream>>>(
      h2, w1T, 8192, 4096, 1024, 1024, 1024, 0, 0, 0, nullptr, g, nullptr,
      fc1_b, nullptr);
  // 12) GEMM5: out = g @ fc2_w + b2 + r2.  grid 256 exact.
  gemm8<2, 2, 4, false, true><<<dim3(8, 32, 1), blk8, LDS2, stream>>>(
      g, w2T, 8192, 1024, 4096, 4096, 4096, 0, 0, 0, out, nullptr, nullptr,
      fc2_b, r2);
}

// Round 5
// 404.948 us; speedup vs baseline: 1.4951x; 1.2768x over previous
//
#include <hip/hip_runtime.h>
#include <math.h>

typedef unsigned short u16;
typedef unsigned int u32;
typedef _Float16 f16x8 __attribute__((ext_vector_type(8)));
typedef float f32x4 __attribute__((ext_vector_type(4)));
typedef u16 u16x4 __attribute__((ext_vector_type(4)));

__device__ __forceinline__ u16 f2h(float x) {
  _Float16 h = (_Float16)x;
  return __builtin_bit_cast(u16, h);
}
__device__ __forceinline__ float h2f(u16 u) {
  return (float)__builtin_bit_cast(_Float16, u);
}

__device__ __forceinline__ void gload16(const void* g, void* l) {
  __builtin_amdgcn_global_load_lds(
      (const __attribute__((address_space(1))) void*)g,
      (__attribute__((address_space(3))) void*)l, 16, 0, 0);
}

// ---------------------------------------------------------------------------
// 8-phase NT GEMM, fp16 inputs / f32 accumulate (mfma_f32_16x16x32_f16).
// A [M,lda] rm, B [N,ldb] rm, C[m][n] = sum_k A[m][k]*B[n][k].
// Tile 256 x (64*JF), BK=64, 8 waves (2Mx4N).  LDS 2 x (32KB A + JF*8KB B),
// XOR slot swizzle (slot ^= row&7), pre-swizzled global source, linear
// global_load_lds dest (rule #21).  Schedule (verified R3/R4): per tile s:
//   p0: read A-frags(+all B); stageA.h0(s+1)->buf[cur^1]
//   p1: stageA.h1(s+1); stageB.h0(s+2)->buf[cur]
//   p2 (JF4): stageB.h1(s+2)
//   last: counted vmcnt(JF) -> drains exactly tile s+1, B(s+2) in flight.
// EPI: 1=scores f32, 2=+resid f32, 3=+bias+gelu->fp16, 4=+bias+resid->f32,
//      5=plain fp16
// ---------------------------------------------------------------------------
template <int JF, int NPH, int EPI, bool SWZ>
__global__ __launch_bounds__(512, 2) void gemm8(
    const u16* __restrict__ A, const u16* __restrict__ B, int M, int N, int K,
    int lda, int ldb, long zsA, long zsB, long zsC, float* __restrict__ outF,
    u16* __restrict__ outU, const float* __restrict__ aux0,
    const float* __restrict__ aux1) {
  constexpr int BUF = 32768 + JF * 8192;  // bytes per double-buffer half
  constexpr int IPP = 8 / NPH;            // i-frags per phase
  extern __shared__ __align__(16) char smem[];

  const int tid = threadIdx.x;
  const int lane = tid & 63;
  const int wave = tid >> 6;
  const int z = blockIdx.z;

  int bx = blockIdx.x, by = blockIdx.y;
  if constexpr (SWZ) {
    const int gx = gridDim.x;
    const int nwg = gx * gridDim.y;
    const int id = by * gx + bx;
    const int q = nwg >> 3;  // nwg % 8 == 0 for all our grids
    const int id2 = (id & 7) * q + (id >> 3);
    bx = id2 % gx;
    by = id2 / gx;
  }
  const long row0 = (long)by * 256;
  const long col0 = (long)bx * (64 * JF);

  const u16* __restrict__ Ab = A + (long)z * zsA;
  const u16* __restrict__ Bb = B + (long)z * zsB;

  // staging lane geometry (pre-swizzled global slot, linear LDS dest)
  const int srow = lane >> 3;
  const int gslot = (lane & 7) ^ srow;
  // fragment lane geometry
  const int fr = lane & 15;
  const int kgrp = lane >> 4;
  const int wm = (wave >> 2) << 7;        // 0 or 128
  const int wn = (wave & 3) * (16 * JF);

  const int nk = K >> 6;

  // hoisted LDS read bases (kk=1 base = kk=0 base ^ 64, carry-free)
  const int slot0 = kgrp ^ (fr & 7);
  const int offA0 = (wm + fr) * 128 + slot0 * 16;
  const int offA1 = offA0 ^ 64;
  const int offB0 = 32768 + (wn + fr) * 128 + slot0 * 16;
  const int offB1 = offB0 ^ 64;

  // hoisted staging bases
  const u16* const gA0 = Ab + (row0 + wave * 16 + srow) * (long)lda + gslot * 8;
  const u16* const gA1 = gA0 + 128 * (long)lda;
  const u16* const gB0 = Bb + (col0 + wave * 16 + srow) * (long)ldb + gslot * 8;
  const u16* const gB1 = gB0 + 128 * (long)ldb;
  char* const dA = smem + wave * 2048 + lane * 16;
  char* const dB = dA + 32768;

  f32x4 acc[8][JF] = {};
  f16x8 bfrag[2][JF];

  auto stageA = [&](int buf, int kt, int h) {
    const long ko = (long)kt * 64;
    const u16* g = (h ? gA1 : gA0) + ko;
    char* d = dA + buf * BUF + (h ? 16384 : 0);
    gload16(g, d);
    gload16(g + 8 * (long)lda, d + 1024);
  };
  auto stageB = [&](int buf, int kt, int h) {
    const long ko = (long)kt * 64;
    const u16* g = (h ? gB1 : gB0) + ko;
    char* d = dB + buf * BUF + (h ? 16384 : 0);
    gload16(g, d);
    gload16(g + 8 * (long)ldb, d + 1024);
  };

  // prologue: tile0 (A+B) -> buf0; tile1's B -> buf1.  Drain tile0 only.
  stageA(0, 0, 0);
  stageA(0, 0, 1);
  stageB(0, 0, 0);
  if constexpr (JF == 4) stageB(0, 0, 1);
  stageB(1, 1, 0);
  if constexpr (JF == 4) stageB(1, 1, 1);
  if constexpr (JF == 4)
    asm volatile("s_waitcnt vmcnt(4)");
  else
    asm volatile("s_waitcnt vmcnt(2)");
  __builtin_amdgcn_s_barrier();

  for (int s = 0; s < nk; ++s) {
    const int cur = s & 1;
    const bool stA = (s + 1 < nk);
    const bool stB = (s + 2 < nk);
    const char* sb = smem + cur * BUF;
    const char* pA0 = sb + offA0;
    const char* pA1 = sb + offA1;
    const char* pB0 = sb + offB0;
    const char* pB1 = sb + offB1;
#pragma unroll
    for (int p = 0; p < NPH; ++p) {
      f16x8 af[IPP][2];
#pragma unroll
      for (int ii = 0; ii < IPP; ++ii) {
        af[ii][0] = *(const f16x8*)(pA0 + (p * IPP + ii) * 2048);
        af[ii][1] = *(const f16x8*)(pA1 + (p * IPP + ii) * 2048);
      }
      if (p == 0) {
#pragma unroll
        for (int j = 0; j < JF; ++j) {
          bfrag[0][j] = *(const f16x8*)(pB0 + j * 2048);
          bfrag[1][j] = *(const f16x8*)(pB1 + j * 2048);
        }
      }
      // staging map
      if (p == 0 && stA) stageA(cur ^ 1, s + 1, 0);
      if (p == 1) {
        if (stA) stageA(cur ^ 1, s + 1, 1);
        if (stB) stageB(cur, s + 2, 0);
      }
      if constexpr (NPH == 4) {
        if (p == 2 && stB) stageB(cur, s + 2, 1);
      }
      __builtin_amdgcn_s_barrier();
      asm volatile("s_waitcnt lgkmcnt(0)");
      __builtin_amdgcn_s_setprio(1);
#pragma unroll
      for (int kk = 0; kk < 2; ++kk)
#pragma unroll
        for (int ii = 0; ii < IPP; ++ii)
#pragma unroll
          for (int j = 0; j < JF; ++j)
            acc[p * IPP + ii][j] = __builtin_amdgcn_mfma_f32_16x16x32_f16(
                af[ii][kk], bfrag[kk][j], acc[p * IPP + ii][j], 0, 0, 0);
      __builtin_amdgcn_s_setprio(0);
      if (p == NPH - 1) {
        if (stB) {
          if constexpr (JF == 4)
            asm volatile("s_waitcnt vmcnt(4)");
          else
            asm volatile("s_waitcnt vmcnt(2)");
        } else {
          asm volatile("s_waitcnt vmcnt(0)");
        }
      }
      __builtin_amdgcn_s_barrier();
    }
  }

  // epilogue: C/D frag layout: col = lane&15 (fr), row = kgrp*4 + r
#pragma unroll
  for (int i = 0; i < 8; ++i) {
#pragma unroll
    for (int j = 0; j < JF; ++j) {
#pragma unroll
      for (int r = 0; r < 4; ++r) {
        const long m = row0 + wm + i * 16 + (kgrp << 2) + r;
        const long n = col0 + wn + j * 16 + fr;
        const float val = acc[i][j][r];
        if constexpr (EPI == 1) {
          outF[(long)z * zsC + m * (long)N + n] = val;
        } else if constexpr (EPI == 2) {
          const long idx = (long)z * zsC + m * (long)N + n;
          outF[idx] = val + aux0[idx];
        } else if constexpr (EPI == 3) {
          const float t = val + aux0[n];
          const float gl = 0.5f * t * (1.0f + erff(t * 0.70710678118654752f));
          outU[m * (long)N + n] = f2h(gl);
        } else if constexpr (EPI == 4) {
          outF[m * (long)N + n] = val + aux0[n] + aux1[m * (long)N + n];
        } else {
          outU[m * (long)N + n] = f2h(val);
        }
      }
    }
  }
}

// ---------------------------------------------------------------------------
// LayerNorm over D=1024, one wave per row, 4 rows/block, fp16 out.
// ---------------------------------------------------------------------------
__global__ __launch_bounds__(256) void ln_k(const float* __restrict__ x,
                                            const float* __restrict__ gw,
                                            const float* __restrict__ bw,
                                            u16* __restrict__ out) {
  const int lane = threadIdx.x & 63;
  const int wv = threadIdx.x >> 6;
  const long row = (long)blockIdx.x * 4 + wv;
  const float* xr = x + row * 1024;
  float4 v[4];
  float s = 0.f, ss = 0.f;
#pragma unroll
  for (int j = 0; j < 4; ++j) {
    v[j] = *(const float4*)(xr + (lane + 64 * j) * 4);
    s += v[j].x + v[j].y + v[j].z + v[j].w;
    ss += v[j].x * v[j].x + v[j].y * v[j].y + v[j].z * v[j].z + v[j].w * v[j].w;
  }
#pragma unroll
  for (int o = 32; o; o >>= 1) {
    s += __shfl_xor(s, o);
    ss += __shfl_xor(ss, o);
  }
  const float mu = s * (1.f / 1024.f);
  const float var = ss * (1.f / 1024.f) - mu * mu;
  const float rs = rsqrtf(var + 1e-5f);
  u16* orow = out + row * 1024;
#pragma unroll
  for (int j = 0; j < 4; ++j) {
    const int n = (lane + 64 * j) * 4;
    const float4 gg = *(const float4*)(gw + n);
    const float4 bb = *(const float4*)(bw + n);
    u16x4 H;
    H[0] = f2h((v[j].x - mu) * rs * gg.x + bb.x);
    H[1] = f2h((v[j].y - mu) * rs * gg.y + bb.y);
    H[2] = f2h((v[j].z - mu) * rs * gg.z + bb.z);
    H[3] = f2h((v[j].w - mu) * rs * gg.w + bb.w);
    *(u16x4*)(orow + n) = H;
  }
}

// ---------------------------------------------------------------------------
// Tiled transpose+convert. in [R,C] -> out [C,R] (per z).
// MODE 0: f32 -> fp16;  MODE 2: fp16 -> fp16.
// ---------------------------------------------------------------------------
template <int MODE>
__global__ __launch_bounds__(256) void transpose_k(const void* __restrict__ in,
                                                   u16* __restrict__ out,
                                                   int R, int C, long zsIn,
                                                   long zsOut) {
  __shared__ float tile[32][33];
  const int z = blockIdx.z;
  const int c0 = blockIdx.x * 32, r0 = blockIdx.y * 32;
#pragma unroll
  for (int i = 0; i < 4; ++i) {
    const int lin = threadIdx.x + 256 * i;
    const int rr = lin >> 5, cc = lin & 31;
    float vv;
    if constexpr (MODE == 2)
      vv = h2f(((const u16*)in + (long)z * zsIn)[(long)(r0 + rr) * C + c0 + cc]);
    else
      vv = ((const float*)in)[(long)(r0 + rr) * C + c0 + cc];
    tile[rr][cc] = vv;
  }
  __syncthreads();
  u16* outz = out + (long)z * zsOut;
#pragma unroll
  for (int i = 0; i < 4; ++i) {
    const int lin = threadIdx.x + 256 * i;
    const int oc = lin >> 5, orr = lin & 31;
    outz[(long)(c0 + oc) * R + (r0 + orr)] = f2h(tile[orr][oc]);
  }
}

// ---------------------------------------------------------------------------
// Row softmax over 2048 cols, f32 in -> fp16 out IN-PLACE (P overwrites the
// first 4 KB of each 16 KB score row; all reads precede first barrier).
// ---------------------------------------------------------------------------
__global__ __launch_bounds__(256) void softmax_k(float* __restrict__ S) {
  const long row = blockIdx.x;
  float* sr = S + row * 2048;
  u16* pr = (u16*)sr;
  const int tid = threadIdx.x;
  const int lane = tid & 63, wv = tid >> 6;
  __shared__ float red[8];
  const float4 v0 = *(const float4*)(sr + tid * 4);
  const float4 v1 = *(const float4*)(sr + 1024 + tid * 4);
  float mx = fmaxf(fmaxf(fmaxf(v0.x, v0.y), fmaxf(v0.z, v0.w)),
                   fmaxf(fmaxf(v1.x, v1.y), fmaxf(v1.z, v1.w)));
#pragma unroll
  for (int o = 32; o; o >>= 1) mx = fmaxf(mx, __shfl_xor(mx, o));
  if (lane == 0) red[wv] = mx;
  __syncthreads();
  mx = fmaxf(fmaxf(red[0], red[1]), fmaxf(red[2], red[3]));
  float e[8];
  e[0] = expf(v0.x - mx); e[1] = expf(v0.y - mx);
  e[2] = expf(v0.z - mx); e[3] = expf(v0.w - mx);
  e[4] = expf(v1.x - mx); e[5] = expf(v1.y - mx);
  e[6] = expf(v1.z - mx); e[7] = expf(v1.w - mx);
  float sm = e[0] + e[1] + e[2] + e[3] + e[4] + e[5] + e[6] + e[7];
#pragma unroll
  for (int o = 32; o; o >>= 1) sm += __shfl_xor(sm, o);
  if (lane == 0) red[4 + wv] = sm;
  __syncthreads();
  sm = red[4] + red[5] + red[6] + red[7];
  const float inv = 1.f / sm;
  u16x4 a, b;
  a[0] = f2h(e[0] * inv); a[1] = f2h(e[1] * inv);
  a[2] = f2h(e[2] * inv); a[3] = f2h(e[3] * inv);
  b[0] = f2h(e[4] * inv); b[1] = f2h(e[5] * inv);
  b[2] = f2h(e[6] * inv); b[3] = f2h(e[7] * inv);
  *(u16x4*)(pr + tid * 4) = a;
  *(u16x4*)(pr + 1024 + tid * 4) = b;
}

// ---------------------------------------------------------------------------
extern "C" void kernel_launch(void* const* d_in, const int* in_sizes, int n_in,
                              void* d_out, int out_size, void* d_ws,
                              size_t ws_size, hipStream_t stream) {
  const float* x     = (const float*)d_in[0];  // [4,2048,1024]
  const float* w_qkv = (const float*)d_in[1];  // [1024,3072]
  const float* fc1_w = (const float*)d_in[2];  // [1024,4096]
  const float* fc1_b = (const float*)d_in[3];  // [4096]
  const float* fc2_w = (const float*)d_in[4];  // [4096,1024]
  const float* fc2_b = (const float*)d_in[5];  // [1024]
  const float* ln1_g = (const float*)d_in[6];
  const float* ln1_b = (const float*)d_in[7];
  const float* ln2_g = (const float*)d_in[8];
  const float* ln2_b = (const float*)d_in[9];
  float* out = (float*)d_out;

  // workspace (peak 160 MB, phase-aliased; all fp16 unless noted)
  char* ws = (char*)d_ws;
  const long MB = 1024L * 1024L;
  u16*   h    = (u16*)(ws + 0);          // 16MB [8192,1024]
  u16*   wqkT = (u16*)(ws + 16 * MB);    //  6MB [3072,1024]
  float* sc   = (float*)(ws + 0);        // 64MB f32 scores (h,wqkT dead)
  u16*   qk   = (u16*)(ws + 64 * MB);    // 32MB [8192,2048] (q|k)
  u16*   vbuf = (u16*)(ws + 96 * MB);    // 16MB [8192,1024]
  u16*   vT   = (u16*)(ws + 112 * MB);   // 16MB [4][1024][2048]
  u16*   w1T  = (u16*)(ws + 144 * MB);   //  8MB [4096,1024]
  u16*   w2T  = (u16*)(ws + 152 * MB);   //  8MB [1024,4096]
  float* r2   = (float*)(ws + 64 * MB);  // 32MB f32 (qk dead after GEMM2)
  u16*   h2   = (u16*)(ws + 96 * MB);    // 16MB (vbuf dead after vT)
  u16*   g    = (u16*)(ws + 0);          // 64MB [8192,4096] (sc/P dead)

  dim3 blk(256);
  dim3 blk8(512);
  const int LDS4 = 131072;  // JF=4: 2 x (32KB A + 32KB B)
  const int LDS2 = 98304;   // JF=2: 2 x (32KB A + 16KB B)
  (void)hipFuncSetAttribute((const void*)gemm8<4, 4, 5, true>,
                            hipFuncAttributeMaxDynamicSharedMemorySize, LDS4);
  (void)hipFuncSetAttribute((const void*)gemm8<2, 2, 5, true>,
                            hipFuncAttributeMaxDynamicSharedMemorySize, LDS2);
  (void)hipFuncSetAttribute((const void*)gemm8<4, 4, 1, true>,
                            hipFuncAttributeMaxDynamicSharedMemorySize, LDS4);
  (void)hipFuncSetAttribute((const void*)gemm8<2, 2, 2, true>,
                            hipFuncAttributeMaxDynamicSharedMemorySize, LDS2);
  (void)hipFuncSetAttribute((const void*)gemm8<4, 4, 3, true>,
                            hipFuncAttributeMaxDynamicSharedMemorySize, LDS4);
  (void)hipFuncSetAttribute((const void*)gemm8<2, 2, 4, true>,
                            hipFuncAttributeMaxDynamicSharedMemorySize, LDS2);

  // 1) LN1 -> h fp16
  ln_k<<<2048, blk, 0, stream>>>(x, ln1_g, ln1_b, h);
  // 2) w_qkv [1024,3072] -> wqkT [3072,1024] fp16 (rows 0..2047 = q|k wts,
  //    rows 2048..3071 = v wts)
  transpose_k<0><<<dim3(3072 / 32, 1024 / 32, 1), blk, 0, stream>>>(
      w_qkv, wqkT, 1024, 3072, 0, 0);
  // 3) qk-GEMM: qk[m][0:2048] = h @ wqk^T.  grid 256 exact, JF4.
  gemm8<4, 4, 5, true><<<dim3(8, 32, 1), blk8, LDS4, stream>>>(
      h, wqkT, 8192, 2048, 1024, 1024, 1024, 0, 0, 0, nullptr, qk, nullptr,
      nullptr);
  // 4) v-GEMM: vbuf = h @ wv^T.  grid 256 exact, JF2.
  gemm8<2, 2, 5, true><<<dim3(8, 32, 1), blk8, LDS2, stream>>>(
      h, wqkT + 2048L * 1024, 8192, 1024, 1024, 1024, 1024, 0, 0, 0, nullptr,
      vbuf, nullptr, nullptr);
  // 5) v -> vT per batch
  transpose_k<2><<<dim3(1024 / 32, 2048 / 32, 4), blk, 0, stream>>>(
      vbuf, vT, 2048, 1024, 2048L * 1024, 1024L * 2048);
  // 6) GEMM2: scores[z] = q[z] @ k[z]^T (fp16, K=1024).  grid 64/z.
  gemm8<4, 4, 1, true><<<dim3(8, 8, 4), blk8, LDS4, stream>>>(
      qk, qk + 1024, 2048, 2048, 1024, 2048, 2048, 2048L * 2048, 2048L * 2048,
      2048L * 2048, sc, nullptr, nullptr, nullptr);
  // 7) softmax in-place: P (fp16, lda=4096 u16) overwrites score rows
  softmax_k<<<8192, blk, 0, stream>>>(sc);
  // 8) GEMM3: attn = P @ vT + resid -> r2.  grid 64/z, JF2.
  gemm8<2, 2, 2, true><<<dim3(8, 8, 4), blk8, LDS2, stream>>>(
      (const u16*)sc, vT, 2048, 1024, 2048, 4096, 2048, 2048L * 4096,
      1024L * 2048, 2048L * 1024, r2, nullptr, x, nullptr);
  // 9) LN2 -> h2 fp16
  ln_k<<<2048, blk, 0, stream>>>(r2, ln2_g, ln2_b, h2);
  // 10) fc1_w -> w1T, fc2_w -> w2T
  transpose_k<0><<<dim3(4096 / 32, 1024 / 32, 1), blk, 0, stream>>>(
      fc1_w, w1T, 1024, 4096, 0, 0);
  transpose_k<0><<<dim3(1024 / 32, 4096 / 32, 1), blk, 0, stream>>>(
      fc2_w, w2T, 4096, 1024, 0, 0);
  // 11) GEMM4: g = gelu(h2 @ fc1_w + b1) fp16.  grid 512 = 2 exact waves.
  gemm8<4, 4, 3, true><<<dim3(16, 32, 1), blk8, LDS4, stream>>>(
      h2, w1T, 8192, 4096, 1024, 1024, 1024, 0, 0, 0, nullptr, g, fc1_b,
      nullptr);
  // 12) GEMM5: out = g @ fc2_w + b2 + r2.  grid 256 exact, JF2.
  gemm8<2, 2, 4, true><<<dim3(8, 32, 1), blk8, LDS2, stream>>>(
      g, w2T, 8192, 1024, 4096, 4096, 4096, 0, 0, 0, out, nullptr, fc2_b, r2);
}